// Round 2
// baseline (1836.018 us; speedup 1.0000x reference)
//
#include <hip/hip_runtime.h>

#define B_ 4
#define C_ 64
#define N_ 8192
#define K_ 20
#define KW 24                    // per-split candidate width (fp32 scan)
#define NSPLIT 4
#define SPLITLEN (N_ / NSPLIT)   // 2048
#define TQ 256
#define TC 128
#define CNT_TOTAL (B_ * N_ * K_) // 655360
#define BN_EPSF 1e-5f

template <typename T, int L>
__device__ __forceinline__ void topk_insert(T (&dist)[L], int (&idxr)[L],
                                            T dd, int ci) {
  if (dd < dist[L - 1]) {
#pragma unroll
    for (int j = L - 1; j >= 1; --j) {
      T dj = dist[j], djm = dist[j - 1];
      int ij = idxr[j], ijm = idxr[j - 1];
      bool ge = (dd >= dj);
      bool gem = (dd >= djm);
      dist[j] = ge ? dj : (gem ? dd : djm);
      idxr[j] = ge ? ij : (gem ? ci : ijm);
    }
    bool ge0 = (dd >= dist[0]);
    idxr[0] = ge0 ? idxr[0] : ci;
    dist[0] = ge0 ? dist[0] : dd;
  }
}

// ---- Kernel 1: transpose x -> xt, per-point sq, y1 = xt*W1^T, y2 = xt*(W2-W1)^T
__global__ __launch_bounds__(256) void prep_kernel(
    const float* __restrict__ x, const float* __restrict__ W,
    float* __restrict__ xt, float* __restrict__ sq,
    float* __restrict__ y1, float* __restrict__ y2) {
  __shared__ float xs[64 * 65];
  __shared__ float Ws[64 * 130];
  int b = blockIdx.x >> 7;
  int n0 = (blockIdx.x & 127) * 64;
  int t = threadIdx.x;
#pragma unroll
  for (int i = 0; i < 16; ++i) {
    int lin = i * 256 + t;
    int c = lin >> 6, j = lin & 63;
    xs[j * 65 + c] = x[((b * 64 + c) * N_) + n0 + j];
  }
#pragma unroll
  for (int i = 0; i < 32; ++i) {
    int lin = i * 256 + t;
    int o = lin >> 7, cc = lin & 127;
    Ws[o * 130 + cc] = W[lin];
  }
  __syncthreads();
#pragma unroll 4
  for (int i = 0; i < 16; ++i) {
    int lin = i * 256 + t;
    int o = lin & 63, nl = lin >> 6;
    float d1 = 0.f, d2 = 0.f;
    const float* xr = &xs[nl * 65];
    const float* wr = &Ws[o * 130];
#pragma unroll
    for (int c = 0; c < 64; ++c) {
      float xv = xr[c];
      float w1 = wr[c], w2 = wr[64 + c];
      d1 = fmaf(xv, w1, d1);
      d2 = fmaf(xv, w2 - w1, d2);
    }
    int n = n0 + nl;
    y1[((b * N_) + n) * 64 + o] = d1;
    y2[((b * N_) + n) * 64 + o] = d2;
  }
#pragma unroll
  for (int i = 0; i < 16; ++i) {
    int lin = i * 256 + t;
    int c = lin & 63, nl = lin >> 6;
    xt[((b * N_) + n0 + nl) * 64 + c] = xs[nl * 65 + c];
  }
  if (t < 64) {
    float s = 0.f;
#pragma unroll
    for (int c = 0; c < 64; ++c) {
      float v = xs[t * 65 + c];
      s = fmaf(v, v, s);
    }
    sq[b * N_ + n0 + t] = s;
  }
}

// ---- Kernel 2: fp32 distance scan + top-24 candidates per split ----
__global__ __launch_bounds__(256) void knn_kernel(
    const float* __restrict__ xt, const float* __restrict__ sq,
    int* __restrict__ pidx) {
  __shared__ float cl[TC * 64];
  __shared__ float sqc[TC];
  int blk = blockIdx.x;
  int split = blk & (NSPLIT - 1);
  int qt = (blk >> 2) & 31;
  int b = blk >> 7;
  int t = threadIdx.x;
  int q = qt * TQ + t;
  const float FINF = __builtin_inff();

  const float* qrow = xt + ((size_t)(b * N_) + q) * 64;
  float qr[64];
#pragma unroll
  for (int u = 0; u < 16; ++u) {
    float4 v = ((const float4*)qrow)[u];
    qr[u * 4 + 0] = v.x; qr[u * 4 + 1] = v.y;
    qr[u * 4 + 2] = v.z; qr[u * 4 + 3] = v.w;
  }
  float sqq = sq[b * N_ + q];
  float dist[KW];
  int idxr[KW];
#pragma unroll
  for (int j = 0; j < KW; ++j) { dist[j] = FINF; idxr[j] = -1; }

  int c0 = split * SPLITLEN;
  for (int tile = 0; tile < SPLITLEN / TC; ++tile) {
    int cbase = c0 + tile * TC;
    const float4* src = (const float4*)(xt + ((size_t)(b * N_) + cbase) * 64);
#pragma unroll
    for (int i = 0; i < 8; ++i) {
      int lin = i * 256 + t;
      ((float4*)cl)[lin] = src[lin];
    }
    if (t < TC) sqc[t] = sq[b * N_ + cbase + t];
    __syncthreads();
#pragma unroll 2
    for (int cc = 0; cc < TC; ++cc) {
      const float4* cr = (const float4*)&cl[cc * 64];
      float d0 = 0.f, d1 = 0.f, d2 = 0.f, d3 = 0.f;
#pragma unroll
      for (int u = 0; u < 16; ++u) {
        float4 v = cr[u];
        d0 = fmaf(v.x, qr[u * 4 + 0], d0);
        d1 = fmaf(v.y, qr[u * 4 + 1], d1);
        d2 = fmaf(v.z, qr[u * 4 + 2], d2);
        d3 = fmaf(v.w, qr[u * 4 + 3], d3);
      }
      float dot = (d0 + d1) + (d2 + d3);
      int cand = cbase + cc;
      float dd = sqq + sqc[cc] - 2.0f * dot;
      if (cand == q) dd = FINF;
      topk_insert<float, KW>(dist, idxr, dd, cand);
    }
    __syncthreads();
  }
  size_t obase = (((size_t)(b * N_) + q) * NSPLIT + split) * KW;
#pragma unroll
  for (int j = 0; j < KW; ++j) pidx[obase + j] = idxr[j];
}

// ---- Kernel 3: fp64 refinement — exact distances on the 96 candidates,
// select true top-20 ----
__global__ __launch_bounds__(64, 1) void refine_kernel(
    const float* __restrict__ xt, const int* __restrict__ pidx,
    int* __restrict__ idxf) {
  int p = blockIdx.x * 64 + threadIdx.x;  // global point id
  int b = p >> 13;
  const double DINF = __builtin_inf();
  const float* qrow = xt + (size_t)p * 64;
  double qd[64];
#pragma unroll
  for (int u = 0; u < 16; ++u) {
    float4 v = ((const float4*)qrow)[u];
    qd[u * 4 + 0] = (double)v.x; qd[u * 4 + 1] = (double)v.y;
    qd[u * 4 + 2] = (double)v.z; qd[u * 4 + 3] = (double)v.w;
  }
  double dist[K_];
  int idxr[K_];
#pragma unroll
  for (int j = 0; j < K_; ++j) { dist[j] = DINF; idxr[j] = -1; }
  const int* pi = pidx + (size_t)p * NSPLIT * KW;
  for (int e = 0; e < NSPLIT * KW; ++e) {
    int ci = pi[e];
    const float* crow = xt + ((size_t)(b * N_) + ci) * 64;
    double acc = 0.0;
#pragma unroll
    for (int u = 0; u < 16; ++u) {
      float4 v = ((const float4*)crow)[u];
      double d0 = qd[u * 4 + 0] - (double)v.x;
      double d1 = qd[u * 4 + 1] - (double)v.y;
      double d2 = qd[u * 4 + 2] - (double)v.z;
      double d3 = qd[u * 4 + 3] - (double)v.w;
      acc = fma(d0, d0, acc);
      acc = fma(d1, d1, acc);
      acc = fma(d2, d2, acc);
      acc = fma(d3, d3, acc);
    }
    topk_insert<double, K_>(dist, idxr, acc, ci);
  }
  int* o = idxf + (size_t)p * K_;
#pragma unroll
  for (int j = 0; j < K_; ++j) o[j] = idxr[j];
}

// ---- Kernel 4: gather h = y1[idx] + y2, per-(b,n,o) max/min, global
// per-channel sum / sumsq ----
__global__ __launch_bounds__(256) void stats_kernel(
    const float* __restrict__ y1, const float* __restrict__ y2,
    const int* __restrict__ idxf, float* __restrict__ maxh,
    float* __restrict__ minh, float* __restrict__ gsum,
    float* __restrict__ gsq) {
  int p = blockIdx.x * 256 + threadIdx.x;
  int b = p >> 13;
  int nb = b * N_;
  const float FINF = __builtin_inff();
  const int* ip = idxf + (size_t)p * K_;
  int nbr[K_];
#pragma unroll
  for (int j = 0; j < K_; ++j) nbr[j] = ip[j];
  const float* y2r = y2 + (size_t)p * 64;

  for (int ch = 0; ch < 4; ++ch) {
    float y2c[16];
#pragma unroll
    for (int u = 0; u < 4; ++u) {
      float4 v = ((const float4*)(y2r + ch * 16))[u];
      y2c[u * 4 + 0] = v.x; y2c[u * 4 + 1] = v.y;
      y2c[u * 4 + 2] = v.z; y2c[u * 4 + 3] = v.w;
    }
    float smax[16], smin[16], ssum[16], ssq[16];
#pragma unroll
    for (int i = 0; i < 16; ++i) {
      smax[i] = -FINF; smin[i] = FINF; ssum[i] = 0.f; ssq[i] = 0.f;
    }
    for (int j = 0; j < K_; ++j) {
      const float* g = y1 + ((size_t)(nb + nbr[j])) * 64 + ch * 16;
#pragma unroll
      for (int u = 0; u < 4; ++u) {
        float4 v = ((const float4*)g)[u];
        float h0 = v.x + y2c[u * 4 + 0];
        float h1 = v.y + y2c[u * 4 + 1];
        float h2 = v.z + y2c[u * 4 + 2];
        float h3 = v.w + y2c[u * 4 + 3];
        smax[u * 4 + 0] = fmaxf(smax[u * 4 + 0], h0);
        smax[u * 4 + 1] = fmaxf(smax[u * 4 + 1], h1);
        smax[u * 4 + 2] = fmaxf(smax[u * 4 + 2], h2);
        smax[u * 4 + 3] = fmaxf(smax[u * 4 + 3], h3);
        smin[u * 4 + 0] = fminf(smin[u * 4 + 0], h0);
        smin[u * 4 + 1] = fminf(smin[u * 4 + 1], h1);
        smin[u * 4 + 2] = fminf(smin[u * 4 + 2], h2);
        smin[u * 4 + 3] = fminf(smin[u * 4 + 3], h3);
        ssum[u * 4 + 0] += h0; ssum[u * 4 + 1] += h1;
        ssum[u * 4 + 2] += h2; ssum[u * 4 + 3] += h3;
        ssq[u * 4 + 0] = fmaf(h0, h0, ssq[u * 4 + 0]);
        ssq[u * 4 + 1] = fmaf(h1, h1, ssq[u * 4 + 1]);
        ssq[u * 4 + 2] = fmaf(h2, h2, ssq[u * 4 + 2]);
        ssq[u * 4 + 3] = fmaf(h3, h3, ssq[u * 4 + 3]);
      }
    }
#pragma unroll
    for (int u = 0; u < 4; ++u) {
      float4 vmax = make_float4(smax[u * 4 + 0], smax[u * 4 + 1],
                                smax[u * 4 + 2], smax[u * 4 + 3]);
      float4 vmin = make_float4(smin[u * 4 + 0], smin[u * 4 + 1],
                                smin[u * 4 + 2], smin[u * 4 + 3]);
      ((float4*)(maxh + (size_t)p * 64 + ch * 16))[u] = vmax;
      ((float4*)(minh + (size_t)p * 64 + ch * 16))[u] = vmin;
    }
#pragma unroll
    for (int i = 0; i < 16; ++i) {
      float s = ssum[i], s2 = ssq[i];
#pragma unroll
      for (int off = 32; off >= 1; off >>= 1) {
        s += __shfl_xor(s, off, 64);
        s2 += __shfl_xor(s2, off, 64);
      }
      if ((threadIdx.x & 63) == 0) {
        atomicAdd(&gsum[ch * 16 + i], s);
        atomicAdd(&gsq[ch * 16 + i], s2);
      }
    }
  }
}

// ---- Kernel 5: affine + relu + max-over-k selection, transposed store ----
__global__ __launch_bounds__(256) void final_kernel(
    const float* __restrict__ maxh, const float* __restrict__ minh,
    const float* __restrict__ gsum, const float* __restrict__ gsq,
    const float* __restrict__ gamma, const float* __restrict__ beta,
    float* __restrict__ out) {
  __shared__ float sc[64], cc_[64];
  __shared__ float tile[64 * 65];
  int b = blockIdx.x >> 7;
  int n0 = (blockIdx.x & 127) * 64;
  int t = threadIdx.x;
  if (t < 64) {
    float mean = gsum[t] * (1.0f / CNT_TOTAL);
    float var = gsq[t] * (1.0f / CNT_TOTAL) - mean * mean;
    float s = gamma[t] * rsqrtf(var + BN_EPSF);
    sc[t] = s;
    cc_[t] = beta[t] - mean * s;
  }
  __syncthreads();
#pragma unroll
  for (int i = 0; i < 16; ++i) {
    int lin = i * 256 + t;
    int o = lin & 63, nl = lin >> 6;
    size_t off = ((size_t)(b * N_) + n0 + nl) * 64 + o;
    float s = sc[o];
    float v = (s >= 0.f) ? maxh[off] : minh[off];
    float val = fmaxf(fmaf(v, s, cc_[o]), 0.f);
    tile[o * 65 + nl] = val;
  }
  __syncthreads();
#pragma unroll
  for (int i = 0; i < 16; ++i) {
    int lin = i * 256 + t;
    int nl = lin & 63, o = lin >> 6;
    out[((size_t)(b * 64) + o) * N_ + n0 + nl] = tile[o * 65 + nl];
  }
}

extern "C" void kernel_launch(void* const* d_in, const int* in_sizes, int n_in,
                              void* d_out, int out_size, void* d_ws,
                              size_t ws_size, hipStream_t stream) {
  const float* x = (const float*)d_in[0];
  const float* W = (const float*)d_in[1];
  const float* gamma = (const float*)d_in[2];
  const float* beta = (const float*)d_in[3];
  float* out = (float*)d_out;

  char* ws = (char*)d_ws;
  size_t off = 0;
  auto alloc = [&](size_t bytes) {
    char* p = ws + off;
    off += (bytes + 255) & ~(size_t)255;
    return p;
  };
  float* xt = (float*)alloc((size_t)B_ * N_ * 64 * 4);
  float* y1 = (float*)alloc((size_t)B_ * N_ * 64 * 4);
  float* y2 = (float*)alloc((size_t)B_ * N_ * 64 * 4);
  float* sq = (float*)alloc((size_t)B_ * N_ * 4);
  int* pidx = (int*)alloc((size_t)B_ * N_ * NSPLIT * KW * 4);  // 12.6 MB
  float* maxh = (float*)alloc((size_t)B_ * N_ * 64 * 4);
  int* idxf = (int*)alloc((size_t)B_ * N_ * K_ * 4);
  float* gsum = (float*)alloc(256);
  float* gsq = (float*)alloc(256);
  // minh aliases pidx (pidx fully consumed by refine before stats runs)
  float* minh = (float*)pidx;

  hipMemsetAsync(gsum, 0, 256, stream);
  hipMemsetAsync(gsq, 0, 256, stream);

  prep_kernel<<<B_ * (N_ / 64), 256, 0, stream>>>(x, W, xt, sq, y1, y2);
  knn_kernel<<<B_ * (N_ / TQ) * NSPLIT, 256, 0, stream>>>(xt, sq, pidx);
  refine_kernel<<<(B_ * N_) / 64, 64, 0, stream>>>(xt, pidx, idxf);
  stats_kernel<<<(B_ * N_) / 256, 256, 0, stream>>>(y1, y2, idxf, maxh, minh,
                                                    gsum, gsq);
  final_kernel<<<B_ * (N_ / 64), 256, 0, stream>>>(maxh, minh, gsum, gsq,
                                                   gamma, beta, out);
}

// Round 3
// 1210.618 us; speedup vs baseline: 1.5166x; 1.5166x over previous
//
#include <hip/hip_runtime.h>

typedef _Float16 half8 __attribute__((ext_vector_type(8)));
typedef float f32x4 __attribute__((ext_vector_type(4)));

#define B_ 4
#define C_ 64
#define N_ 8192
#define K_ 20
#define LCELL 10                  // per-lane per-query sorted list depth
#define NCAND (16 * LCELL)        // 160 candidates per query into refine
#define CNT_TOTAL (B_ * N_ * K_)  // 655360
#define BN_EPSF 1e-5f

// ---- Kernel 1: transpose x -> xt (f32 + f16), per-point sq,
// y1 = xt*W1^T, y2 = xt*(W2-W1)^T
__global__ __launch_bounds__(256) void prep_kernel(
    const float* __restrict__ x, const float* __restrict__ W,
    float* __restrict__ xt, _Float16* __restrict__ xt16,
    float* __restrict__ sq, float* __restrict__ y1, float* __restrict__ y2) {
  __shared__ float xs[64 * 65];
  __shared__ float Ws[64 * 130];
  int b = blockIdx.x >> 7;
  int n0 = (blockIdx.x & 127) * 64;
  int t = threadIdx.x;
#pragma unroll
  for (int i = 0; i < 16; ++i) {
    int lin = i * 256 + t;
    int c = lin >> 6, j = lin & 63;
    xs[j * 65 + c] = x[((b * 64 + c) * N_) + n0 + j];
  }
#pragma unroll
  for (int i = 0; i < 32; ++i) {
    int lin = i * 256 + t;
    int o = lin >> 7, cc = lin & 127;
    Ws[o * 130 + cc] = W[lin];
  }
  __syncthreads();
#pragma unroll 4
  for (int i = 0; i < 16; ++i) {
    int lin = i * 256 + t;
    int o = lin & 63, nl = lin >> 6;
    float d1 = 0.f, d2 = 0.f;
    const float* xr = &xs[nl * 65];
    const float* wr = &Ws[o * 130];
#pragma unroll
    for (int c = 0; c < 64; ++c) {
      float xv = xr[c];
      float w1 = wr[c], w2 = wr[64 + c];
      d1 = fmaf(xv, w1, d1);
      d2 = fmaf(xv, w2 - w1, d2);
    }
    int n = n0 + nl;
    y1[((b * N_) + n) * 64 + o] = d1;
    y2[((b * N_) + n) * 64 + o] = d2;
  }
#pragma unroll
  for (int i = 0; i < 16; ++i) {
    int lin = i * 256 + t;
    int c = lin & 63, nl = lin >> 6;
    float v = xs[nl * 65 + c];
    size_t o = ((size_t)(b * N_) + n0 + nl) * 64 + c;
    xt[o] = v;
    xt16[o] = (_Float16)v;
  }
  if (t < 64) {
    float s = 0.f;
#pragma unroll
    for (int c = 0; c < 64; ++c) {
      float v = xs[t * 65 + c];
      s = fmaf(v, v, s);
    }
    sq[b * N_ + n0 + t] = s;
  }
}

// ---- Kernel 2: MFMA distance scan + in-C-layout per-cell top-10 selection.
// Wave owns 16 queries; lane owns candidate class col=lane&15 and queries
// row = quad*4+r (MFMA C layout, verified mapping). Key = sqc - 2*dot
// (sqq constant per query -> ranking-equivalent). No LDS at all.
__global__ __launch_bounds__(256, 2) void knn_mfma_kernel(
    const _Float16* __restrict__ xt16, const float* __restrict__ sq,
    int* __restrict__ pidx) {
  int t = threadIdx.x;
  int wave = t >> 6;
  int lane = t & 63;
  int col = lane & 15;
  int quad = lane >> 4;
  int b = blockIdx.x >> 7;
  int q0 = (blockIdx.x & 127) * 64 + wave * 16;
  size_t bbase = (size_t)b * N_;
  const float FINF = __builtin_inff();

  // A fragments: A[m=col][k=quad*8+j] -> query row q0+col
  const _Float16* arow = xt16 + (bbase + q0 + col) * 64;
  half8 A0 = *(const half8*)(arow + quad * 8);
  half8 A1 = *(const half8*)(arow + 32 + quad * 8);

  float dl[4][LCELL];
  int il[4][LCELL];
#pragma unroll
  for (int r = 0; r < 4; ++r)
#pragma unroll
    for (int j = 0; j < LCELL; ++j) { dl[r][j] = FINF; il[r][j] = 0; }
  int myq[4];
#pragma unroll
  for (int r = 0; r < 4; ++r) myq[r] = q0 + quad * 4 + r;

  // software-pipelined B fragments (next-tile loads issued before inserts)
  const _Float16* brow0 = xt16 + (bbase + col) * 64;
  half8 B0 = *(const half8*)(brow0 + quad * 8);
  half8 B1 = *(const half8*)(brow0 + 32 + quad * 8);
  float sqc = sq[bbase + col];

  for (int ct = 0; ct < N_ / 16; ++ct) {
    int nct = (ct + 1) & (N_ / 16 - 1);
    const _Float16* nbrow = xt16 + (bbase + nct * 16 + col) * 64;
    half8 nB0 = *(const half8*)(nbrow + quad * 8);
    half8 nB1 = *(const half8*)(nbrow + 32 + quad * 8);
    float nsqc = sq[bbase + nct * 16 + col];

    f32x4 acc = {0.f, 0.f, 0.f, 0.f};
    acc = __builtin_amdgcn_mfma_f32_16x16x32_f16(A0, B0, acc, 0, 0, 0);
    acc = __builtin_amdgcn_mfma_f32_16x16x32_f16(A1, B1, acc, 0, 0, 0);
    int cand = ct * 16 + col;
#pragma unroll
    for (int r = 0; r < 4; ++r) {
      float key = fmaf(acc[r], -2.0f, sqc);
      if (cand == myq[r]) key = FINF;  // self-exclusion
      if (key < dl[r][LCELL - 1]) {
#pragma unroll
        for (int j = LCELL - 1; j >= 1; --j) {
          float dj = dl[r][j], djm = dl[r][j - 1];
          int ij = il[r][j], ijm = il[r][j - 1];
          bool ge = (key >= dj);
          bool gem = (key >= djm);
          dl[r][j] = ge ? dj : (gem ? key : djm);
          il[r][j] = ge ? ij : (gem ? ct : ijm);
        }
        bool g0 = (key >= dl[r][0]);
        il[r][0] = g0 ? il[r][0] : ct;
        dl[r][0] = g0 ? dl[r][0] : key;
      }
    }
    B0 = nB0; B1 = nB1; sqc = nsqc;
  }
#pragma unroll
  for (int r = 0; r < 4; ++r) {
    int* o = pidx + (bbase + myq[r]) * NCAND + col * LCELL;
#pragma unroll
    for (int j = 0; j < LCELL; ++j) o[j] = il[r][j] * 16 + col;
  }
}

// ---- Kernel 3: fp64 refinement over 160 candidates, exact distances,
// index tie-break (lower index wins, matching lax.top_k) ----
__device__ __forceinline__ bool better(double dd, int ci, double dj, int ij) {
  return dd < dj || (dd == dj && ci < ij);
}

__global__ __launch_bounds__(64, 1) void refine_kernel(
    const float* __restrict__ xt, const int* __restrict__ pidx,
    int* __restrict__ idxf) {
  int p = blockIdx.x * 64 + threadIdx.x;  // global point id
  int b = p >> 13;
  const double DINF = __builtin_inf();
  const float* qrow = xt + (size_t)p * 64;
  double qd[64];
#pragma unroll
  for (int u = 0; u < 16; ++u) {
    float4 v = ((const float4*)qrow)[u];
    qd[u * 4 + 0] = (double)v.x; qd[u * 4 + 1] = (double)v.y;
    qd[u * 4 + 2] = (double)v.z; qd[u * 4 + 3] = (double)v.w;
  }
  double dist[K_];
  int idxr[K_];
#pragma unroll
  for (int j = 0; j < K_; ++j) { dist[j] = DINF; idxr[j] = 0x7fffffff; }
  const int* pi = pidx + (size_t)p * NCAND;
  for (int e = 0; e < NCAND; ++e) {
    int ci = pi[e];
    const float* crow = xt + ((size_t)(b * N_) + ci) * 64;
    double acc = 0.0;
#pragma unroll
    for (int u = 0; u < 16; ++u) {
      float4 v = ((const float4*)crow)[u];
      double d0 = qd[u * 4 + 0] - (double)v.x;
      double d1 = qd[u * 4 + 1] - (double)v.y;
      double d2 = qd[u * 4 + 2] - (double)v.z;
      double d3 = qd[u * 4 + 3] - (double)v.w;
      acc = fma(d0, d0, acc);
      acc = fma(d1, d1, acc);
      acc = fma(d2, d2, acc);
      acc = fma(d3, d3, acc);
    }
    if (ci == p - b * N_) continue;  // safety (self excluded upstream)
    if (better(acc, ci, dist[K_ - 1], idxr[K_ - 1])) {
#pragma unroll
      for (int j = K_ - 1; j >= 1; --j) {
        double dj = dist[j], djm = dist[j - 1];
        int ij = idxr[j], ijm = idxr[j - 1];
        bool ge = !better(acc, ci, dj, ij);
        bool gem = !better(acc, ci, djm, ijm);
        dist[j] = ge ? dj : (gem ? acc : djm);
        idxr[j] = ge ? ij : (gem ? ci : ijm);
      }
      bool g0 = !better(acc, ci, dist[0], idxr[0]);
      idxr[0] = g0 ? idxr[0] : ci;
      dist[0] = g0 ? dist[0] : acc;
    }
  }
  int* o = idxf + (size_t)p * K_;
#pragma unroll
  for (int j = 0; j < K_; ++j) o[j] = idxr[j];
}

// ---- Kernel 4: gather h = y1[idx] + y2, per-(b,n,o) max/min, global
// per-channel sum / sumsq ----
__global__ __launch_bounds__(256) void stats_kernel(
    const float* __restrict__ y1, const float* __restrict__ y2,
    const int* __restrict__ idxf, float* __restrict__ maxh,
    float* __restrict__ minh, float* __restrict__ gsum,
    float* __restrict__ gsq) {
  int p = blockIdx.x * 256 + threadIdx.x;
  int b = p >> 13;
  int nb = b * N_;
  const float FINF = __builtin_inff();
  const int* ip = idxf + (size_t)p * K_;
  int nbr[K_];
#pragma unroll
  for (int j = 0; j < K_; ++j) nbr[j] = ip[j];
  const float* y2r = y2 + (size_t)p * 64;

  for (int ch = 0; ch < 4; ++ch) {
    float y2c[16];
#pragma unroll
    for (int u = 0; u < 4; ++u) {
      float4 v = ((const float4*)(y2r + ch * 16))[u];
      y2c[u * 4 + 0] = v.x; y2c[u * 4 + 1] = v.y;
      y2c[u * 4 + 2] = v.z; y2c[u * 4 + 3] = v.w;
    }
    float smax[16], smin[16], ssum[16], ssq[16];
#pragma unroll
    for (int i = 0; i < 16; ++i) {
      smax[i] = -FINF; smin[i] = FINF; ssum[i] = 0.f; ssq[i] = 0.f;
    }
    for (int j = 0; j < K_; ++j) {
      const float* g = y1 + ((size_t)(nb + nbr[j])) * 64 + ch * 16;
#pragma unroll
      for (int u = 0; u < 4; ++u) {
        float4 v = ((const float4*)g)[u];
        float h0 = v.x + y2c[u * 4 + 0];
        float h1 = v.y + y2c[u * 4 + 1];
        float h2 = v.z + y2c[u * 4 + 2];
        float h3 = v.w + y2c[u * 4 + 3];
        smax[u * 4 + 0] = fmaxf(smax[u * 4 + 0], h0);
        smax[u * 4 + 1] = fmaxf(smax[u * 4 + 1], h1);
        smax[u * 4 + 2] = fmaxf(smax[u * 4 + 2], h2);
        smax[u * 4 + 3] = fmaxf(smax[u * 4 + 3], h3);
        smin[u * 4 + 0] = fminf(smin[u * 4 + 0], h0);
        smin[u * 4 + 1] = fminf(smin[u * 4 + 1], h1);
        smin[u * 4 + 2] = fminf(smin[u * 4 + 2], h2);
        smin[u * 4 + 3] = fminf(smin[u * 4 + 3], h3);
        ssum[u * 4 + 0] += h0; ssum[u * 4 + 1] += h1;
        ssum[u * 4 + 2] += h2; ssum[u * 4 + 3] += h3;
        ssq[u * 4 + 0] = fmaf(h0, h0, ssq[u * 4 + 0]);
        ssq[u * 4 + 1] = fmaf(h1, h1, ssq[u * 4 + 1]);
        ssq[u * 4 + 2] = fmaf(h2, h2, ssq[u * 4 + 2]);
        ssq[u * 4 + 3] = fmaf(h3, h3, ssq[u * 4 + 3]);
      }
    }
#pragma unroll
    for (int u = 0; u < 4; ++u) {
      float4 vmax = make_float4(smax[u * 4 + 0], smax[u * 4 + 1],
                                smax[u * 4 + 2], smax[u * 4 + 3]);
      float4 vmin = make_float4(smin[u * 4 + 0], smin[u * 4 + 1],
                                smin[u * 4 + 2], smin[u * 4 + 3]);
      ((float4*)(maxh + (size_t)p * 64 + ch * 16))[u] = vmax;
      ((float4*)(minh + (size_t)p * 64 + ch * 16))[u] = vmin;
    }
#pragma unroll
    for (int i = 0; i < 16; ++i) {
      float s = ssum[i], s2 = ssq[i];
#pragma unroll
      for (int off = 32; off >= 1; off >>= 1) {
        s += __shfl_xor(s, off, 64);
        s2 += __shfl_xor(s2, off, 64);
      }
      if ((threadIdx.x & 63) == 0) {
        atomicAdd(&gsum[ch * 16 + i], s);
        atomicAdd(&gsq[ch * 16 + i], s2);
      }
    }
  }
}

// ---- Kernel 5: affine + relu + max-over-k selection, transposed store ----
__global__ __launch_bounds__(256) void final_kernel(
    const float* __restrict__ maxh, const float* __restrict__ minh,
    const float* __restrict__ gsum, const float* __restrict__ gsq,
    const float* __restrict__ gamma, const float* __restrict__ beta,
    float* __restrict__ out) {
  __shared__ float sc[64], cc_[64];
  __shared__ float tile[64 * 65];
  int b = blockIdx.x >> 7;
  int n0 = (blockIdx.x & 127) * 64;
  int t = threadIdx.x;
  if (t < 64) {
    float mean = gsum[t] * (1.0f / CNT_TOTAL);
    float var = gsq[t] * (1.0f / CNT_TOTAL) - mean * mean;
    float s = gamma[t] * rsqrtf(var + BN_EPSF);
    sc[t] = s;
    cc_[t] = beta[t] - mean * s;
  }
  __syncthreads();
#pragma unroll
  for (int i = 0; i < 16; ++i) {
    int lin = i * 256 + t;
    int o = lin & 63, nl = lin >> 6;
    size_t off = ((size_t)(b * N_) + n0 + nl) * 64 + o;
    float s = sc[o];
    float v = (s >= 0.f) ? maxh[off] : minh[off];
    float val = fmaxf(fmaf(v, s, cc_[o]), 0.f);
    tile[o * 65 + nl] = val;
  }
  __syncthreads();
#pragma unroll
  for (int i = 0; i < 16; ++i) {
    int lin = i * 256 + t;
    int nl = lin & 63, o = lin >> 6;
    out[((size_t)(b * 64) + o) * N_ + n0 + nl] = tile[o * 65 + nl];
  }
}

extern "C" void kernel_launch(void* const* d_in, const int* in_sizes, int n_in,
                              void* d_out, int out_size, void* d_ws,
                              size_t ws_size, hipStream_t stream) {
  const float* x = (const float*)d_in[0];
  const float* W = (const float*)d_in[1];
  const float* gamma = (const float*)d_in[2];
  const float* beta = (const float*)d_in[3];
  float* out = (float*)d_out;

  char* ws = (char*)d_ws;
  size_t off = 0;
  auto alloc = [&](size_t bytes) {
    char* p = ws + off;
    off += (bytes + 255) & ~(size_t)255;
    return p;
  };
  float* xt = (float*)alloc((size_t)B_ * N_ * 64 * 4);
  _Float16* xt16 = (_Float16*)alloc((size_t)B_ * N_ * 64 * 2);
  float* y1 = (float*)alloc((size_t)B_ * N_ * 64 * 4);
  float* y2 = (float*)alloc((size_t)B_ * N_ * 64 * 4);
  float* sq = (float*)alloc((size_t)B_ * N_ * 4);
  int* pidx = (int*)alloc((size_t)B_ * N_ * NCAND * 4);  // 21 MB
  float* maxh = (float*)alloc((size_t)B_ * N_ * 64 * 4);
  int* idxf = (int*)alloc((size_t)B_ * N_ * K_ * 4);
  float* gsum = (float*)alloc(256);
  float* gsq = (float*)alloc(256);
  // minh aliases pidx (pidx fully consumed by refine before stats runs)
  float* minh = (float*)pidx;

  hipMemsetAsync(gsum, 0, 256, stream);
  hipMemsetAsync(gsq, 0, 256, stream);

  prep_kernel<<<B_ * (N_ / 64), 256, 0, stream>>>(x, W, xt, xt16, sq, y1, y2);
  knn_mfma_kernel<<<B_ * (N_ / 64), 256, 0, stream>>>(xt16, sq, pidx);
  refine_kernel<<<(B_ * N_) / 64, 64, 0, stream>>>(xt, pidx, idxf);
  stats_kernel<<<(B_ * N_) / 256, 256, 0, stream>>>(y1, y2, idxf, maxh, minh,
                                                    gsum, gsq);
  final_kernel<<<B_ * (N_ / 64), 256, 0, stream>>>(maxh, minh, gsum, gsq,
                                                   gamma, beta, out);
}